// Round 1
// baseline (901.487 us; speedup 1.0000x reference)
//
#include <hip/hip_runtime.h>
#include <hip/hip_bf16.h>

#define ALPHA 0.2f
#define IN_DIM 256
#define HD 256      // HEADS*OUT_DIM
#define HEADS 4
#define ODIM 64

__device__ __forceinline__ float lrelu(float x) { return x > 0.f ? x : ALPHA * x; }

// ---------------------------------------------------------------------------
// K1: ft = feat @ W^T  (ft[n,c] = sum_k feat[n,k]*W[c,k]), plus fused
//     a1[n,h] = sum_d ft[n,h,d]*attn_l[h,d], a2 likewise with attn_r.
// Block: 256 threads, 16 rows of feat. ty=tid>>6 picks 4 rows, tx=tid&63
// with cc in 0..3 picks col = cc*64+tx. 4x4 register tile per thread.
// ---------------------------------------------------------------------------
__global__ __launch_bounds__(256) void gemm_kernel(
    const float* __restrict__ feat, const float* __restrict__ W,
    const float* __restrict__ attn_l, const float* __restrict__ attn_r,
    float* __restrict__ ft, float* __restrict__ a1, float* __restrict__ a2) {
  __shared__ float ftile[16][IN_DIM];
  const int tid = threadIdx.x;
  const int row0 = blockIdx.x * 16;

  // stage 16x256 f32 tile (coalesced float4)
#pragma unroll
  for (int i = 0; i < 4; ++i) {
    int j = tid + i * 256;       // float4 index 0..1023
    int flat = j * 4;
    int r = flat >> 8, c = flat & 255;
    *(float4*)&ftile[r][c] =
        *(const float4*)&feat[(size_t)(row0 + r) * IN_DIM + c];
  }
  __syncthreads();

  const int tx = tid & 63, ty = tid >> 6;
  float acc[4][4];
#pragma unroll
  for (int rr = 0; rr < 4; ++rr)
#pragma unroll
    for (int cc = 0; cc < 4; ++cc) acc[rr][cc] = 0.f;

  for (int k0 = 0; k0 < IN_DIM; k0 += 4) {
    float4 w4[4], f4[4];
#pragma unroll
    for (int cc = 0; cc < 4; ++cc)
      w4[cc] = *(const float4*)&W[(size_t)(cc * 64 + tx) * IN_DIM + k0];
#pragma unroll
    for (int rr = 0; rr < 4; ++rr)
      f4[rr] = *(const float4*)&ftile[ty * 4 + rr][k0];
#pragma unroll
    for (int rr = 0; rr < 4; ++rr)
#pragma unroll
      for (int cc = 0; cc < 4; ++cc) {
        acc[rr][cc] += f4[rr].x * w4[cc].x;
        acc[rr][cc] += f4[rr].y * w4[cc].y;
        acc[rr][cc] += f4[rr].z * w4[cc].z;
        acc[rr][cc] += f4[rr].w * w4[cc].w;
      }
  }

  // epilogue: write ft, reduce a1/a2 per (row, head) across the 64-lane wave
  float al[4], ar[4];
#pragma unroll
  for (int cc = 0; cc < 4; ++cc) {
    al[cc] = attn_l[cc * 64 + tx];
    ar[cc] = attn_r[cc * 64 + tx];
  }
#pragma unroll
  for (int rr = 0; rr < 4; ++rr) {
    int row = row0 + ty * 4 + rr;
#pragma unroll
    for (int cc = 0; cc < 4; ++cc) {
      float v = acc[rr][cc];
      ft[(size_t)row * HD + cc * 64 + tx] = v;
      float v1 = v * al[cc];
      float v2 = v * ar[cc];
#pragma unroll
      for (int o = 32; o; o >>= 1) {
        v1 += __shfl_xor(v1, o);
        v2 += __shfl_xor(v2, o);
      }
      if (tx == 0) {
        a1[(size_t)row * HEADS + cc] = v1;
        a2[(size_t)row * HEADS + cc] = v2;
      }
    }
  }
}

// ---------------------------------------------------------------------------
// K2: per-edge scores e[i,h] = leakyrelu(a1[src,h]+a2[dst,h]); fused degree
//     histogram for CSR build.
// ---------------------------------------------------------------------------
__global__ __launch_bounds__(256) void edge_kernel(
    const float* __restrict__ a1, const float* __restrict__ a2,
    const int* __restrict__ src, const int* __restrict__ dst,
    float* __restrict__ e, int* __restrict__ deg, int E) {
  int i = blockIdx.x * blockDim.x + threadIdx.x;
  if (i >= E) return;
  int s_ = src[i], d_ = dst[i];
  float4 va = ((const float4*)a1)[s_];
  float4 vb = ((const float4*)a2)[d_];
  float4 r;
  r.x = lrelu(va.x + vb.x);
  r.y = lrelu(va.y + vb.y);
  r.z = lrelu(va.z + vb.z);
  r.w = lrelu(va.w + vb.w);
  ((float4*)e)[i] = r;
  atomicAdd(&deg[d_], 1);
}

// ---------------------------------------------------------------------------
// K3: single-block exclusive scan of deg -> rowptr (n=50000, 1024 threads)
// ---------------------------------------------------------------------------
__global__ __launch_bounds__(1024) void scan_kernel(
    const int* __restrict__ deg, int* __restrict__ rowptr, int n) {
  __shared__ int buf[1024];
  const int tid = threadIdx.x;
  const int chunk = (n + 1023) >> 10;
  const int b = tid * chunk;
  const int e_ = min(b + chunk, n);
  int s = 0;
  for (int i = b; i < e_; ++i) s += deg[i];
  buf[tid] = s;
  __syncthreads();
  // Hillis-Steele inclusive scan
  for (int d = 1; d < 1024; d <<= 1) {
    int v = (tid >= d) ? buf[tid - d] : 0;
    __syncthreads();
    buf[tid] += v;
    __syncthreads();
  }
  int off = (tid > 0) ? buf[tid - 1] : 0;  // exclusive prefix
  for (int i = b; i < e_; ++i) {
    rowptr[i] = off;
    off += deg[i];
  }
  if (b < n && e_ == n) rowptr[n] = off;
}

// ---------------------------------------------------------------------------
// K4: scatter edge ids into CSR buckets
// ---------------------------------------------------------------------------
__global__ __launch_bounds__(256) void scatter_kernel(
    const int* __restrict__ dst, const int* __restrict__ rowptr,
    int* __restrict__ cursor, int* __restrict__ eid, int E) {
  int i = blockIdx.x * blockDim.x + threadIdx.x;
  if (i >= E) return;
  int d_ = dst[i];
  int pos = atomicAdd(&cursor[d_], 1);
  eid[rowptr[d_] + pos] = i;
}

// ---------------------------------------------------------------------------
// K5: per-dst-node softmax + weighted aggregation + ELU.
// One 256-thread block per node; thread owns output dim (h=tid>>6, d=tid&63).
// max/sum via 64-lane wave shuffle (one wave == one head). No atomics.
// ---------------------------------------------------------------------------
__global__ __launch_bounds__(256) void aggregate_kernel(
    const float* __restrict__ ft, const float* __restrict__ e,
    const int* __restrict__ src, const int* __restrict__ rowptr,
    const int* __restrict__ eid, float* __restrict__ out) {
  const int n = blockIdx.x;
  const int tid = threadIdx.x;
  const int h = tid >> 6;
  const int lane = tid & 63;
  const int start = rowptr[n];
  const int cnt = rowptr[n + 1] - start;

  float mx = -1e30f;
  for (int j = lane; j < cnt; j += 64) {
    int i = eid[start + j];
    mx = fmaxf(mx, e[(size_t)i * HEADS + h]);
  }
#pragma unroll
  for (int o = 32; o; o >>= 1) mx = fmaxf(mx, __shfl_xor(mx, o));

  float sm = 0.f;
  for (int j = lane; j < cnt; j += 64) {
    int i = eid[start + j];
    sm += __expf(e[(size_t)i * HEADS + h] - mx);
  }
#pragma unroll
  for (int o = 32; o; o >>= 1) sm += __shfl_xor(sm, o);
  float inv = (cnt > 0) ? 1.f / sm : 0.f;

  float acc = 0.f;
  for (int j = 0; j < cnt; ++j) {
    int i = eid[start + j];
    float a = __expf(e[(size_t)i * HEADS + h] - mx) * inv;
    acc += a * ft[(size_t)src[i] * HD + tid];
  }
  out[(size_t)n * HD + tid] = acc > 0.f ? acc : (__expf(acc) - 1.f);
}

// ---------------------------------------------------------------------------
extern "C" void kernel_launch(void* const* d_in, const int* in_sizes, int n_in,
                              void* d_out, int out_size, void* d_ws, size_t ws_size,
                              hipStream_t stream) {
  const float* feat   = (const float*)d_in[0];
  const int*   src    = (const int*)d_in[1];
  const int*   dst    = (const int*)d_in[2];
  const float* W      = (const float*)d_in[3];
  const float* attn_l = (const float*)d_in[4];
  const float* attn_r = (const float*)d_in[5];
  float* out = (float*)d_out;

  const int N = in_sizes[0] / IN_DIM;   // 50000
  const int E = in_sizes[1];            // 800000

  // workspace layout (256B-aligned regions)
  size_t off = 0;
  auto alloc = [&](size_t bytes) -> void* {
    void* p = (char*)d_ws + off;
    off = (off + bytes + 255) & ~(size_t)255;
    return p;
  };
  float* ft     = (float*)alloc((size_t)N * HD * 4);
  float* a1     = (float*)alloc((size_t)N * HEADS * 4);
  float* a2     = (float*)alloc((size_t)N * HEADS * 4);
  float* e      = (float*)alloc((size_t)E * HEADS * 4);
  int*   deg    = (int*)alloc((size_t)2 * N * 4);   // deg + cursor contiguous
  int*   cursor = deg + N;
  int*   rowptr = (int*)alloc((size_t)(N + 1) * 4);
  int*   eid    = (int*)alloc((size_t)E * 4);
  (void)ws_size;

  hipMemsetAsync(deg, 0, (size_t)2 * N * 4, stream);

  const int eb = (E + 255) / 256;
  gemm_kernel<<<N / 16, 256, 0, stream>>>(feat, W, attn_l, attn_r, ft, a1, a2);
  edge_kernel<<<eb, 256, 0, stream>>>(a1, a2, src, dst, e, deg, E);
  scan_kernel<<<1, 1024, 0, stream>>>(deg, rowptr, N);
  scatter_kernel<<<eb, 256, 0, stream>>>(dst, rowptr, cursor, eid, E);
  aggregate_kernel<<<N, 256, 0, stream>>>(ft, e, src, rowptr, eid, out);
}

// Round 3
// 491.472 us; speedup vs baseline: 1.8343x; 1.8343x over previous
//
#include <hip/hip_runtime.h>
#include <hip/hip_bf16.h>

#define ALPHA 0.2f
#define IN_DIM 256
#define HD 256      // HEADS*OUT_DIM
#define HEADS 4

typedef short short8 __attribute__((ext_vector_type(8)));
typedef float f32x4 __attribute__((ext_vector_type(4)));

__device__ __forceinline__ float lrelu(float x) { return x > 0.f ? x : ALPHA * x; }

__device__ __forceinline__ unsigned short f2bf(float x) {  // RTNE f32->bf16
  unsigned int u = __builtin_bit_cast(unsigned int, x);
  unsigned int r = (u + 0x7fffu + ((u >> 16) & 1u)) >> 16;
  return (unsigned short)r;
}
__device__ __forceinline__ float bf2f(unsigned short h) {
  unsigned int u = ((unsigned int)h) << 16;
  return __builtin_bit_cast(float, u);
}

// ---------------------------------------------------------------------------
// K0: W (f32 [256][256]) -> hi/lo bf16 pair (hi = bf16(x), lo = bf16(x-hi))
// ---------------------------------------------------------------------------
__global__ __launch_bounds__(256) void wcvt_kernel(
    const float* __restrict__ W, unsigned short* __restrict__ whi,
    unsigned short* __restrict__ wlo) {
  int i = (blockIdx.x * 256 + threadIdx.x) * 4;
  float4 f = *(const float4*)&W[i];
  unsigned short h[4], l[4];
  float ff[4] = {f.x, f.y, f.z, f.w};
#pragma unroll
  for (int k = 0; k < 4; ++k) {
    h[k] = f2bf(ff[k]);
    l[k] = f2bf(ff[k] - bf2f(h[k]));
  }
  uint2 oh, ol;
  oh.x = (unsigned int)h[0] | ((unsigned int)h[1] << 16);
  oh.y = (unsigned int)h[2] | ((unsigned int)h[3] << 16);
  ol.x = (unsigned int)l[0] | ((unsigned int)l[1] << 16);
  ol.y = (unsigned int)l[2] | ((unsigned int)l[3] << 16);
  *(uint2*)&whi[i] = oh;
  *(uint2*)&wlo[i] = ol;
}

// ---------------------------------------------------------------------------
// K1: split-precision MFMA projection:
//     ft = (Ahi+Alo) @ (Bhi+Blo)^T ~= Ahi@Bhi + Ahi@Blo + Alo@Bhi  (f32 acc)
// Block = 256 thr (4 waves), tile 64 rows x 256 cols; wave w owns head w.
// A hi/lo tiles in LDS, XOR-swizzled (byte ^= (row&7)<<4). B from L2.
// Fused a1/a2 epilogue from f32 accumulators.
// ---------------------------------------------------------------------------
__global__ __launch_bounds__(256) void gemm_mfma(
    const float* __restrict__ feat, const unsigned short* __restrict__ whi,
    const unsigned short* __restrict__ wlo,
    const float* __restrict__ attn_l, const float* __restrict__ attn_r,
    unsigned short* __restrict__ ftb, float* __restrict__ a1,
    float* __restrict__ a2, int N) {
  __shared__ uint4 ldsh[2048];  // A-hi: 64 rows x 512B, swizzled
  __shared__ uint4 ldsl[2048];  // A-lo
  const int tid = threadIdx.x;
  const int row0 = blockIdx.x * 64;

#pragma unroll
  for (int it = 0; it < 8; ++it) {
    int ci = tid + it * 256;
    int row = ci >> 5, c16 = ci & 31;
    int grow = row0 + row;
    uint4 ph = uint4{0u, 0u, 0u, 0u}, pl = uint4{0u, 0u, 0u, 0u};
    if (grow < N) {
      const float* gp = &feat[(size_t)grow * IN_DIM + c16 * 8];
      float4 f0 = *(const float4*)gp;
      float4 f1 = *(const float4*)(gp + 4);
      float ff[8] = {f0.x, f0.y, f0.z, f0.w, f1.x, f1.y, f1.z, f1.w};
      unsigned int hh[8], ll[8];
#pragma unroll
      for (int k = 0; k < 8; ++k) {
        unsigned short h = f2bf(ff[k]);
        hh[k] = h;
        ll[k] = f2bf(ff[k] - bf2f(h));
      }
      ph.x = hh[0] | (hh[1] << 16); ph.y = hh[2] | (hh[3] << 16);
      ph.z = hh[4] | (hh[5] << 16); ph.w = hh[6] | (hh[7] << 16);
      pl.x = ll[0] | (ll[1] << 16); pl.y = ll[2] | (ll[3] << 16);
      pl.z = ll[4] | (ll[5] << 16); pl.w = ll[6] | (ll[7] << 16);
    }
    int idx = (row * 512 + ((c16 * 16) ^ ((row & 7) << 4))) >> 4;
    ldsh[idx] = ph;
    ldsl[idx] = pl;
  }
  __syncthreads();

  const int lane = tid & 63;
  const int w = tid >> 6;   // wave id == head id == N-quadrant
  const int m15 = lane & 15;
  const int g = lane >> 4;  // k-group 0..3

  f32x4 acc[4][4];
#pragma unroll
  for (int mt = 0; mt < 4; ++mt)
#pragma unroll
    for (int nt = 0; nt < 4; ++nt) acc[mt][nt] = f32x4{0.f, 0.f, 0.f, 0.f};

  const uint4* wh4 = (const uint4*)whi;  // 32 uint4 per W row
  const uint4* wl4 = (const uint4*)wlo;
  for (int ks = 0; ks < 8; ++ks) {       // K = 8 * 32
    short8 ah[4], al_[4], bh[4], bl[4];
#pragma unroll
    for (int mt = 0; mt < 4; ++mt) {
      int row = mt * 16 + m15;
      int idx = (row * 512 + ((ks * 64 + g * 16) ^ ((row & 7) << 4))) >> 4;
      ah[mt] = __builtin_bit_cast(short8, ldsh[idx]);
      al_[mt] = __builtin_bit_cast(short8, ldsl[idx]);
    }
#pragma unroll
    for (int nt = 0; nt < 4; ++nt) {
      int n = w * 64 + nt * 16 + m15;
      bh[nt] = __builtin_bit_cast(short8, wh4[n * 32 + ks * 4 + g]);
      bl[nt] = __builtin_bit_cast(short8, wl4[n * 32 + ks * 4 + g]);
    }
#pragma unroll
    for (int mt = 0; mt < 4; ++mt)
#pragma unroll
      for (int nt = 0; nt < 4; ++nt) {
        acc[mt][nt] = __builtin_amdgcn_mfma_f32_16x16x32_bf16(
            ah[mt], bh[nt], acc[mt][nt], 0, 0, 0);
        acc[mt][nt] = __builtin_amdgcn_mfma_f32_16x16x32_bf16(
            ah[mt], bl[nt], acc[mt][nt], 0, 0, 0);
        acc[mt][nt] = __builtin_amdgcn_mfma_f32_16x16x32_bf16(
            al_[mt], bh[nt], acc[mt][nt], 0, 0, 0);
      }
  }

  // epilogue: ft (bf16) + fused a1/a2 (f32)
  float al[4], ar[4];
#pragma unroll
  for (int nt = 0; nt < 4; ++nt) {
    al[nt] = attn_l[w * 64 + nt * 16 + m15];
    ar[nt] = attn_r[w * 64 + nt * 16 + m15];
  }
#pragma unroll
  for (int mt = 0; mt < 4; ++mt) {
#pragma unroll
    for (int r = 0; r < 4; ++r) {
      int rloc = mt * 16 + g * 4 + r;  // C/D: row=(lane>>4)*4+reg (m89)
      int row = row0 + rloc;
      float v1 = 0.f, v2 = 0.f;
#pragma unroll
      for (int nt = 0; nt < 4; ++nt) {
        float v = acc[mt][nt][r];
        v1 += v * al[nt];
        v2 += v * ar[nt];
        if (row < N)
          ftb[(size_t)row * HD + w * 64 + nt * 16 + m15] = f2bf(v);
      }
#pragma unroll
      for (int o = 8; o; o >>= 1) {
        v1 += __shfl_xor(v1, o);
        v2 += __shfl_xor(v2, o);
      }
      if (m15 == 0 && row < N) {
        a1[(size_t)row * HEADS + w] = v1;
        a2[(size_t)row * HEADS + w] = v2;
      }
    }
  }
}

// ---------------------------------------------------------------------------
// K2: per-edge scores + degree histogram
// ---------------------------------------------------------------------------
__global__ __launch_bounds__(256) void edge_kernel(
    const float* __restrict__ a1, const float* __restrict__ a2,
    const int* __restrict__ src, const int* __restrict__ dst,
    float* __restrict__ e, int* __restrict__ deg, int E) {
  int i = blockIdx.x * blockDim.x + threadIdx.x;
  if (i >= E) return;
  int s_ = src[i], d_ = dst[i];
  float4 va = ((const float4*)a1)[s_];
  float4 vb = ((const float4*)a2)[d_];
  float4 r;
  r.x = lrelu(va.x + vb.x);
  r.y = lrelu(va.y + vb.y);
  r.z = lrelu(va.z + vb.z);
  r.w = lrelu(va.w + vb.w);
  ((float4*)e)[i] = r;
  atomicAdd(&deg[d_], 1);
}

// ---------------------------------------------------------------------------
// K3: single-block exclusive scan deg -> rowptr
// ---------------------------------------------------------------------------
__global__ __launch_bounds__(1024) void scan_kernel(
    const int* __restrict__ deg, int* __restrict__ rowptr, int n) {
  __shared__ int buf[1024];
  const int tid = threadIdx.x;
  const int chunk = (n + 1023) >> 10;
  const int b = tid * chunk;
  const int e_ = min(b + chunk, n);
  int s = 0;
  for (int i = b; i < e_; ++i) s += deg[i];
  buf[tid] = s;
  __syncthreads();
  for (int d = 1; d < 1024; d <<= 1) {
    int v = (tid >= d) ? buf[tid - d] : 0;
    __syncthreads();
    buf[tid] += v;
    __syncthreads();
  }
  int off = (tid > 0) ? buf[tid - 1] : 0;
  for (int i = b; i < e_; ++i) {
    rowptr[i] = off;
    off += deg[i];
  }
  if (b < n && e_ == n) rowptr[n] = off;
}

// ---------------------------------------------------------------------------
// K4: scatter edge ids into CSR buckets
// ---------------------------------------------------------------------------
__global__ __launch_bounds__(256) void scatter_kernel(
    const int* __restrict__ dst, const int* __restrict__ rowptr,
    int* __restrict__ cursor, int* __restrict__ eid, int E) {
  int i = blockIdx.x * blockDim.x + threadIdx.x;
  if (i >= E) return;
  int d_ = dst[i];
  int pos = atomicAdd(&cursor[d_], 1);
  eid[rowptr[d_] + pos] = i;
}

// ---------------------------------------------------------------------------
// K5: per-dst softmax + weighted aggregation + ELU (ft in bf16)
// ---------------------------------------------------------------------------
__global__ __launch_bounds__(256) void aggregate_kernel(
    const unsigned short* __restrict__ ftb, const float* __restrict__ e,
    const int* __restrict__ src, const int* __restrict__ rowptr,
    const int* __restrict__ eid, float* __restrict__ out) {
  const int n = blockIdx.x;
  const int tid = threadIdx.x;
  const int h = tid >> 6;
  const int lane = tid & 63;
  const int start = rowptr[n];
  const int cnt = rowptr[n + 1] - start;

  float mx = -1e30f;
  for (int j = lane; j < cnt; j += 64) {
    int i = eid[start + j];
    mx = fmaxf(mx, e[(size_t)i * HEADS + h]);
  }
#pragma unroll
  for (int o = 32; o; o >>= 1) mx = fmaxf(mx, __shfl_xor(mx, o));

  float sm = 0.f;
  for (int j = lane; j < cnt; j += 64) {
    int i = eid[start + j];
    sm += __expf(e[(size_t)i * HEADS + h] - mx);
  }
#pragma unroll
  for (int o = 32; o; o >>= 1) sm += __shfl_xor(sm, o);
  float inv = (cnt > 0) ? 1.f / sm : 0.f;

  float acc = 0.f;
  for (int j = 0; j < cnt; ++j) {
    int i = eid[start + j];
    float a = __expf(e[(size_t)i * HEADS + h] - mx) * inv;
    acc += a * bf2f(ftb[(size_t)src[i] * HD + tid]);
  }
  out[(size_t)n * HD + tid] = acc > 0.f ? acc : (__expf(acc) - 1.f);
}

// ---------------------------------------------------------------------------
extern "C" void kernel_launch(void* const* d_in, const int* in_sizes, int n_in,
                              void* d_out, int out_size, void* d_ws, size_t ws_size,
                              hipStream_t stream) {
  const float* feat   = (const float*)d_in[0];
  const int*   src    = (const int*)d_in[1];
  const int*   dst    = (const int*)d_in[2];
  const float* W      = (const float*)d_in[3];
  const float* attn_l = (const float*)d_in[4];
  const float* attn_r = (const float*)d_in[5];
  float* out = (float*)d_out;

  const int N = in_sizes[0] / IN_DIM;   // 50000
  const int E = in_sizes[1];            // 800000

  size_t off = 0;
  auto alloc = [&](size_t bytes) -> void* {
    void* p = (char*)d_ws + off;
    off = (off + bytes + 255) & ~(size_t)255;
    return p;
  };
  unsigned short* ftb = (unsigned short*)alloc((size_t)N * HD * 2);
  unsigned short* whi = (unsigned short*)alloc((size_t)HD * IN_DIM * 2);
  unsigned short* wlo = (unsigned short*)alloc((size_t)HD * IN_DIM * 2);
  float* a1     = (float*)alloc((size_t)N * HEADS * 4);
  float* a2     = (float*)alloc((size_t)N * HEADS * 4);
  float* e      = (float*)alloc((size_t)E * HEADS * 4);
  int*   deg    = (int*)alloc((size_t)2 * N * 4);   // deg + cursor
  int*   cursor = deg + N;
  int*   rowptr = (int*)alloc((size_t)(N + 1) * 4);
  int*   eid    = (int*)alloc((size_t)E * 4);
  (void)ws_size;

  hipMemsetAsync(deg, 0, (size_t)2 * N * 4, stream);

  const int eb = (E + 255) / 256;
  wcvt_kernel<<<64, 256, 0, stream>>>(W, whi, wlo);
  gemm_mfma<<<(N + 63) / 64, 256, 0, stream>>>(feat, whi, wlo, attn_l, attn_r,
                                               ftb, a1, a2, N);
  edge_kernel<<<eb, 256, 0, stream>>>(a1, a2, src, dst, e, deg, E);
  scan_kernel<<<1, 1024, 0, stream>>>(deg, rowptr, N);
  scatter_kernel<<<eb, 256, 0, stream>>>(dst, rowptr, cursor, eid, E);
  aggregate_kernel<<<N, 256, 0, stream>>>(ftb, e, src, rowptr, eid, out);
}

// Round 4
// 323.549 us; speedup vs baseline: 2.7862x; 1.5190x over previous
//
#include <hip/hip_runtime.h>
#include <hip/hip_bf16.h>

#define ALPHA 0.2f
#define IN_DIM 256
#define HD 256      // HEADS*OUT_DIM
#define HEADS 4
#define MAXE 256    // LDS-cached weights per node (fallback recompute beyond)

typedef short short8 __attribute__((ext_vector_type(8)));
typedef float f32x4 __attribute__((ext_vector_type(4)));

__device__ __forceinline__ float lrelu(float x) { return x > 0.f ? x : ALPHA * x; }

__device__ __forceinline__ unsigned short f2bf(float x) {  // RTNE f32->bf16
  unsigned int u = __builtin_bit_cast(unsigned int, x);
  unsigned int r = (u + 0x7fffu + ((u >> 16) & 1u)) >> 16;
  return (unsigned short)r;
}
__device__ __forceinline__ float bf2f(unsigned short h) {
  unsigned int u = ((unsigned int)h) << 16;
  return __builtin_bit_cast(float, u);
}

// ---------------------------------------------------------------------------
// K0: W (f32 [256][256]) -> hi/lo bf16 pair (hi = bf16(x), lo = bf16(x-hi))
// ---------------------------------------------------------------------------
__global__ __launch_bounds__(256) void wcvt_kernel(
    const float* __restrict__ W, unsigned short* __restrict__ whi,
    unsigned short* __restrict__ wlo) {
  int i = (blockIdx.x * 256 + threadIdx.x) * 4;
  float4 f = *(const float4*)&W[i];
  unsigned short h[4], l[4];
  float ff[4] = {f.x, f.y, f.z, f.w};
#pragma unroll
  for (int k = 0; k < 4; ++k) {
    h[k] = f2bf(ff[k]);
    l[k] = f2bf(ff[k] - bf2f(h[k]));
  }
  uint2 oh, ol;
  oh.x = (unsigned int)h[0] | ((unsigned int)h[1] << 16);
  oh.y = (unsigned int)h[2] | ((unsigned int)h[3] << 16);
  ol.x = (unsigned int)l[0] | ((unsigned int)l[1] << 16);
  ol.y = (unsigned int)l[2] | ((unsigned int)l[3] << 16);
  *(uint2*)&whi[i] = oh;
  *(uint2*)&wlo[i] = ol;
}

// ---------------------------------------------------------------------------
// K0b: degree histogram
// ---------------------------------------------------------------------------
__global__ __launch_bounds__(256) void deg_kernel(
    const int* __restrict__ dst, int* __restrict__ deg, int E) {
  int i = blockIdx.x * blockDim.x + threadIdx.x;
  if (i < E) atomicAdd(&deg[dst[i]], 1);
}

// ---------------------------------------------------------------------------
// K1: split-precision MFMA projection:
//     ft = (Ahi+Alo) @ (Bhi+Blo)^T ~= Ahi@Bhi + Ahi@Blo + Alo@Bhi  (f32 acc)
// Block = 256 thr (4 waves), tile 64 rows x 256 cols; wave w owns head w.
// A hi/lo tiles in LDS, XOR-swizzled (byte ^= (row&7)<<4). B from L2.
// Fused a1/a2 epilogue from f32 accumulators.
// ---------------------------------------------------------------------------
__global__ __launch_bounds__(256) void gemm_mfma(
    const float* __restrict__ feat, const unsigned short* __restrict__ whi,
    const unsigned short* __restrict__ wlo,
    const float* __restrict__ attn_l, const float* __restrict__ attn_r,
    unsigned short* __restrict__ ftb, float* __restrict__ a1,
    float* __restrict__ a2, int N) {
  __shared__ uint4 ldsh[2048];  // A-hi: 64 rows x 512B, swizzled
  __shared__ uint4 ldsl[2048];  // A-lo
  const int tid = threadIdx.x;
  const int row0 = blockIdx.x * 64;

#pragma unroll
  for (int it = 0; it < 8; ++it) {
    int ci = tid + it * 256;
    int row = ci >> 5, c16 = ci & 31;
    int grow = row0 + row;
    uint4 ph = uint4{0u, 0u, 0u, 0u}, pl = uint4{0u, 0u, 0u, 0u};
    if (grow < N) {
      const float* gp = &feat[(size_t)grow * IN_DIM + c16 * 8];
      float4 f0 = *(const float4*)gp;
      float4 f1 = *(const float4*)(gp + 4);
      float ff[8] = {f0.x, f0.y, f0.z, f0.w, f1.x, f1.y, f1.z, f1.w};
      unsigned int hh[8], ll[8];
#pragma unroll
      for (int k = 0; k < 8; ++k) {
        unsigned short h = f2bf(ff[k]);
        hh[k] = h;
        ll[k] = f2bf(ff[k] - bf2f(h));
      }
      ph.x = hh[0] | (hh[1] << 16); ph.y = hh[2] | (hh[3] << 16);
      ph.z = hh[4] | (hh[5] << 16); ph.w = hh[6] | (hh[7] << 16);
      pl.x = ll[0] | (ll[1] << 16); pl.y = ll[2] | (ll[3] << 16);
      pl.z = ll[4] | (ll[5] << 16); pl.w = ll[6] | (ll[7] << 16);
    }
    int idx = (row * 512 + ((c16 * 16) ^ ((row & 7) << 4))) >> 4;
    ldsh[idx] = ph;
    ldsl[idx] = pl;
  }
  __syncthreads();

  const int lane = tid & 63;
  const int w = tid >> 6;   // wave id == head id == N-quadrant
  const int m15 = lane & 15;
  const int g = lane >> 4;  // k-group 0..3

  f32x4 acc[4][4];
#pragma unroll
  for (int mt = 0; mt < 4; ++mt)
#pragma unroll
    for (int nt = 0; nt < 4; ++nt) acc[mt][nt] = f32x4{0.f, 0.f, 0.f, 0.f};

  const uint4* wh4 = (const uint4*)whi;  // 32 uint4 per W row
  const uint4* wl4 = (const uint4*)wlo;
  for (int ks = 0; ks < 8; ++ks) {       // K = 8 * 32
    short8 ah[4], al_[4], bh[4], bl[4];
#pragma unroll
    for (int mt = 0; mt < 4; ++mt) {
      int row = mt * 16 + m15;
      int idx = (row * 512 + ((ks * 64 + g * 16) ^ ((row & 7) << 4))) >> 4;
      ah[mt] = __builtin_bit_cast(short8, ldsh[idx]);
      al_[mt] = __builtin_bit_cast(short8, ldsl[idx]);
    }
#pragma unroll
    for (int nt = 0; nt < 4; ++nt) {
      int n = w * 64 + nt * 16 + m15;
      bh[nt] = __builtin_bit_cast(short8, wh4[n * 32 + ks * 4 + g]);
      bl[nt] = __builtin_bit_cast(short8, wl4[n * 32 + ks * 4 + g]);
    }
#pragma unroll
    for (int mt = 0; mt < 4; ++mt)
#pragma unroll
      for (int nt = 0; nt < 4; ++nt) {
        acc[mt][nt] = __builtin_amdgcn_mfma_f32_16x16x32_bf16(
            ah[mt], bh[nt], acc[mt][nt], 0, 0, 0);
        acc[mt][nt] = __builtin_amdgcn_mfma_f32_16x16x32_bf16(
            ah[mt], bl[nt], acc[mt][nt], 0, 0, 0);
        acc[mt][nt] = __builtin_amdgcn_mfma_f32_16x16x32_bf16(
            al_[mt], bh[nt], acc[mt][nt], 0, 0, 0);
      }
  }

  // epilogue: ft (bf16) + fused a1/a2 (f32)
  float al[4], ar[4];
#pragma unroll
  for (int nt = 0; nt < 4; ++nt) {
    al[nt] = attn_l[w * 64 + nt * 16 + m15];
    ar[nt] = attn_r[w * 64 + nt * 16 + m15];
  }
#pragma unroll
  for (int mt = 0; mt < 4; ++mt) {
#pragma unroll
    for (int r = 0; r < 4; ++r) {
      int rloc = mt * 16 + g * 4 + r;  // C/D: row=(lane>>4)*4+reg (m89)
      int row = row0 + rloc;
      float v1 = 0.f, v2 = 0.f;
#pragma unroll
      for (int nt = 0; nt < 4; ++nt) {
        float v = acc[mt][nt][r];
        v1 += v * al[nt];
        v2 += v * ar[nt];
        if (row < N)
          ftb[(size_t)row * HD + w * 64 + nt * 16 + m15] = f2bf(v);
      }
#pragma unroll
      for (int o = 8; o; o >>= 1) {
        v1 += __shfl_xor(v1, o);
        v2 += __shfl_xor(v2, o);
      }
      if (m15 == 0 && row < N) {
        a1[(size_t)row * HEADS + w] = v1;
        a2[(size_t)row * HEADS + w] = v2;
      }
    }
  }
}

// ---------------------------------------------------------------------------
// K3: single-block exclusive scan deg -> rowptr
// ---------------------------------------------------------------------------
__global__ __launch_bounds__(1024) void scan_kernel(
    const int* __restrict__ deg, int* __restrict__ rowptr, int n) {
  __shared__ int buf[1024];
  const int tid = threadIdx.x;
  const int chunk = (n + 1023) >> 10;
  const int b = tid * chunk;
  const int e_ = min(b + chunk, n);
  int s = 0;
  for (int i = b; i < e_; ++i) s += deg[i];
  buf[tid] = s;
  __syncthreads();
  for (int d = 1; d < 1024; d <<= 1) {
    int v = (tid >= d) ? buf[tid - d] : 0;
    __syncthreads();
    buf[tid] += v;
    __syncthreads();
  }
  int off = (tid > 0) ? buf[tid - 1] : 0;
  for (int i = b; i < e_; ++i) {
    rowptr[i] = off;
    off += deg[i];
  }
  if (b < n && e_ == n) rowptr[n] = off;
}

// ---------------------------------------------------------------------------
// K4: fused edge-score + CSR scatter.
// e[h] = leakyrelu(a1[src,h]+a2[dst,h]); write into CSR slot of dst along
// with src id. Removes the eid indirection from the aggregation hot loop.
// ---------------------------------------------------------------------------
__global__ __launch_bounds__(256) void edge_scatter_kernel(
    const float* __restrict__ a1, const float* __restrict__ a2,
    const int* __restrict__ src, const int* __restrict__ dst,
    const int* __restrict__ rowptr, int* __restrict__ cursor,
    float* __restrict__ csr_e, int* __restrict__ csr_src, int E) {
  int i = blockIdx.x * blockDim.x + threadIdx.x;
  if (i >= E) return;
  int s_ = src[i], d_ = dst[i];
  float4 va = ((const float4*)a1)[s_];
  float4 vb = ((const float4*)a2)[d_];
  float4 r;
  r.x = lrelu(va.x + vb.x);
  r.y = lrelu(va.y + vb.y);
  r.z = lrelu(va.z + vb.z);
  r.w = lrelu(va.w + vb.w);
  int pos = rowptr[d_] + atomicAdd(&cursor[d_], 1);
  ((float4*)csr_e)[pos] = r;
  csr_src[pos] = s_;
}

// ---------------------------------------------------------------------------
// K5: per-dst softmax + weighted aggregation + ELU.
// Weights cached in LDS (computed in the sum pass); gather loop unrolled x4
// for 4 outstanding ft-row loads per wave.
// ---------------------------------------------------------------------------
__global__ __launch_bounds__(256) void aggregate_kernel(
    const unsigned short* __restrict__ ftb, const float* __restrict__ csr_e,
    const int* __restrict__ csr_src, const int* __restrict__ rowptr,
    float* __restrict__ out) {
  __shared__ float exw[HEADS][MAXE];
  const int n = blockIdx.x;
  const int tid = threadIdx.x;
  const int h = tid >> 6;
  const int lane = tid & 63;
  const int start = rowptr[n];
  const int cnt = rowptr[n + 1] - start;

  float mx = -1e30f;
  for (int j = lane; j < cnt; j += 64)
    mx = fmaxf(mx, csr_e[(size_t)(start + j) * HEADS + h]);
#pragma unroll
  for (int o = 32; o; o >>= 1) mx = fmaxf(mx, __shfl_xor(mx, o));

  float sm = 0.f;
  for (int j = lane; j < cnt; j += 64) {
    float ex = __expf(csr_e[(size_t)(start + j) * HEADS + h] - mx);
    if (j < MAXE) exw[h][j] = ex;
    sm += ex;
  }
#pragma unroll
  for (int o = 32; o; o >>= 1) sm += __shfl_xor(sm, o);
  float inv = (cnt > 0) ? 1.f / sm : 0.f;
  // exw[h][*] written and read by the same wave (head h) — no barrier needed

  const int lim = min(cnt, MAXE);
  float acc = 0.f;
  int j = 0;
  for (; j + 4 <= lim; j += 4) {
    int s0 = csr_src[start + j + 0];
    int s1 = csr_src[start + j + 1];
    int s2 = csr_src[start + j + 2];
    int s3 = csr_src[start + j + 3];
    float w0 = exw[h][j + 0], w1 = exw[h][j + 1];
    float w2 = exw[h][j + 2], w3 = exw[h][j + 3];
    float f0 = bf2f(ftb[(size_t)s0 * HD + tid]);
    float f1 = bf2f(ftb[(size_t)s1 * HD + tid]);
    float f2 = bf2f(ftb[(size_t)s2 * HD + tid]);
    float f3 = bf2f(ftb[(size_t)s3 * HD + tid]);
    acc += w0 * f0 + w1 * f1 + w2 * f2 + w3 * f3;
  }
  for (; j < cnt; ++j) {
    float w = (j < MAXE) ? exw[h][j]
                         : __expf(csr_e[(size_t)(start + j) * HEADS + h] - mx);
    acc += w * bf2f(ftb[(size_t)csr_src[start + j] * HD + tid]);
  }
  acc *= inv;
  out[(size_t)n * HD + tid] = acc > 0.f ? acc : (__expf(acc) - 1.f);
}

// ---------------------------------------------------------------------------
extern "C" void kernel_launch(void* const* d_in, const int* in_sizes, int n_in,
                              void* d_out, int out_size, void* d_ws, size_t ws_size,
                              hipStream_t stream) {
  const float* feat   = (const float*)d_in[0];
  const int*   src    = (const int*)d_in[1];
  const int*   dst    = (const int*)d_in[2];
  const float* W      = (const float*)d_in[3];
  const float* attn_l = (const float*)d_in[4];
  const float* attn_r = (const float*)d_in[5];
  float* out = (float*)d_out;

  const int N = in_sizes[0] / IN_DIM;   // 50000
  const int E = in_sizes[1];            // 800000

  size_t off = 0;
  auto alloc = [&](size_t bytes) -> void* {
    void* p = (char*)d_ws + off;
    off = (off + bytes + 255) & ~(size_t)255;
    return p;
  };
  unsigned short* ftb = (unsigned short*)alloc((size_t)N * HD * 2);
  unsigned short* whi = (unsigned short*)alloc((size_t)HD * IN_DIM * 2);
  unsigned short* wlo = (unsigned short*)alloc((size_t)HD * IN_DIM * 2);
  float* a1      = (float*)alloc((size_t)N * HEADS * 4);
  float* a2      = (float*)alloc((size_t)N * HEADS * 4);
  float* csr_e   = (float*)alloc((size_t)E * HEADS * 4);
  int*   csr_src = (int*)alloc((size_t)E * 4);
  int*   deg     = (int*)alloc((size_t)2 * N * 4);   // deg + cursor
  int*   cursor  = deg + N;
  int*   rowptr  = (int*)alloc((size_t)(N + 1) * 4);
  (void)ws_size;

  hipMemsetAsync(deg, 0, (size_t)2 * N * 4, stream);

  const int eb = (E + 255) / 256;
  wcvt_kernel<<<64, 256, 0, stream>>>(W, whi, wlo);
  deg_kernel<<<eb, 256, 0, stream>>>(dst, deg, E);
  scan_kernel<<<1, 1024, 0, stream>>>(deg, rowptr, N);
  gemm_mfma<<<(N + 63) / 64, 256, 0, stream>>>(feat, whi, wlo, attn_l, attn_r,
                                               ftb, a1, a2, N);
  edge_scatter_kernel<<<eb, 256, 0, stream>>>(a1, a2, src, dst, rowptr, cursor,
                                              csr_e, csr_src, E);
  aggregate_kernel<<<N, 256, 0, stream>>>(ftb, csr_e, csr_src, rowptr, out);
}

// Round 5
// 279.221 us; speedup vs baseline: 3.2286x; 1.1588x over previous
//
#include <hip/hip_runtime.h>
#include <hip/hip_bf16.h>

#define ALPHA 0.2f
#define IN_DIM 256
#define HD 256      // HEADS*OUT_DIM
#define HEADS 4
#define MAXE 256    // LDS-cached weights per node (fallback recompute beyond)

typedef short short8 __attribute__((ext_vector_type(8)));
typedef float f32x4 __attribute__((ext_vector_type(4)));

__device__ __forceinline__ float lrelu(float x) { return x > 0.f ? x : ALPHA * x; }

__device__ __forceinline__ unsigned short f2bf(float x) {  // RTNE f32->bf16
  unsigned int u = __builtin_bit_cast(unsigned int, x);
  unsigned int r = (u + 0x7fffu + ((u >> 16) & 1u)) >> 16;
  return (unsigned short)r;
}
__device__ __forceinline__ float bf2f(unsigned short h) {
  unsigned int u = ((unsigned int)h) << 16;
  return __builtin_bit_cast(float, u);
}
// packed bf16 pair -> f32 (low / high element)
__device__ __forceinline__ float bflo(unsigned int u) {
  return __builtin_bit_cast(float, u << 16);
}
__device__ __forceinline__ float bfhi(unsigned int u) {
  return __builtin_bit_cast(float, u & 0xffff0000u);
}

// ---------------------------------------------------------------------------
// K0: W (f32 [256][256]) -> hi/lo bf16 pair (hi = bf16(x), lo = bf16(x-hi))
// ---------------------------------------------------------------------------
__global__ __launch_bounds__(256) void wcvt_kernel(
    const float* __restrict__ W, unsigned short* __restrict__ whi,
    unsigned short* __restrict__ wlo) {
  int i = (blockIdx.x * 256 + threadIdx.x) * 4;
  float4 f = *(const float4*)&W[i];
  unsigned short h[4], l[4];
  float ff[4] = {f.x, f.y, f.z, f.w};
#pragma unroll
  for (int k = 0; k < 4; ++k) {
    h[k] = f2bf(ff[k]);
    l[k] = f2bf(ff[k] - bf2f(h[k]));
  }
  uint2 oh, ol;
  oh.x = (unsigned int)h[0] | ((unsigned int)h[1] << 16);
  oh.y = (unsigned int)h[2] | ((unsigned int)h[3] << 16);
  ol.x = (unsigned int)l[0] | ((unsigned int)l[1] << 16);
  ol.y = (unsigned int)l[2] | ((unsigned int)l[3] << 16);
  *(uint2*)&whi[i] = oh;
  *(uint2*)&wlo[i] = ol;
}

// ---------------------------------------------------------------------------
// K0b: degree histogram
// ---------------------------------------------------------------------------
__global__ __launch_bounds__(256) void deg_kernel(
    const int* __restrict__ dst, int* __restrict__ deg, int E) {
  int i = blockIdx.x * blockDim.x + threadIdx.x;
  if (i < E) atomicAdd(&deg[dst[i]], 1);
}

// ---------------------------------------------------------------------------
// K1: split-precision MFMA projection:
//     ft = (Ahi+Alo) @ (Bhi+Blo)^T ~= Ahi@Bhi + Ahi@Blo + Alo@Bhi  (f32 acc)
// Block = 256 thr (4 waves), tile 64 rows x 256 cols; wave w owns head w.
// A hi/lo tiles in LDS, XOR-swizzled (byte ^= (row&7)<<4). B from L2.
// Fused a1/a2 epilogue from f32 accumulators.
// ---------------------------------------------------------------------------
__global__ __launch_bounds__(256) void gemm_mfma(
    const float* __restrict__ feat, const unsigned short* __restrict__ whi,
    const unsigned short* __restrict__ wlo,
    const float* __restrict__ attn_l, const float* __restrict__ attn_r,
    unsigned short* __restrict__ ftb, float* __restrict__ a1,
    float* __restrict__ a2, int N) {
  __shared__ uint4 ldsh[2048];  // A-hi: 64 rows x 512B, swizzled
  __shared__ uint4 ldsl[2048];  // A-lo
  const int tid = threadIdx.x;
  const int row0 = blockIdx.x * 64;

#pragma unroll
  for (int it = 0; it < 8; ++it) {
    int ci = tid + it * 256;
    int row = ci >> 5, c16 = ci & 31;
    int grow = row0 + row;
    uint4 ph = uint4{0u, 0u, 0u, 0u}, pl = uint4{0u, 0u, 0u, 0u};
    if (grow < N) {
      const float* gp = &feat[(size_t)grow * IN_DIM + c16 * 8];
      float4 f0 = *(const float4*)gp;
      float4 f1 = *(const float4*)(gp + 4);
      float ff[8] = {f0.x, f0.y, f0.z, f0.w, f1.x, f1.y, f1.z, f1.w};
      unsigned int hh[8], ll[8];
#pragma unroll
      for (int k = 0; k < 8; ++k) {
        unsigned short h = f2bf(ff[k]);
        hh[k] = h;
        ll[k] = f2bf(ff[k] - bf2f(h));
      }
      ph.x = hh[0] | (hh[1] << 16); ph.y = hh[2] | (hh[3] << 16);
      ph.z = hh[4] | (hh[5] << 16); ph.w = hh[6] | (hh[7] << 16);
      pl.x = ll[0] | (ll[1] << 16); pl.y = ll[2] | (ll[3] << 16);
      pl.z = ll[4] | (ll[5] << 16); pl.w = ll[6] | (ll[7] << 16);
    }
    int idx = (row * 512 + ((c16 * 16) ^ ((row & 7) << 4))) >> 4;
    ldsh[idx] = ph;
    ldsl[idx] = pl;
  }
  __syncthreads();

  const int lane = tid & 63;
  const int w = tid >> 6;   // wave id == head id == N-quadrant
  const int m15 = lane & 15;
  const int g = lane >> 4;  // k-group 0..3

  f32x4 acc[4][4];
#pragma unroll
  for (int mt = 0; mt < 4; ++mt)
#pragma unroll
    for (int nt = 0; nt < 4; ++nt) acc[mt][nt] = f32x4{0.f, 0.f, 0.f, 0.f};

  const uint4* wh4 = (const uint4*)whi;  // 32 uint4 per W row
  const uint4* wl4 = (const uint4*)wlo;
  for (int ks = 0; ks < 8; ++ks) {       // K = 8 * 32
    short8 ah[4], al_[4], bh[4], bl[4];
#pragma unroll
    for (int mt = 0; mt < 4; ++mt) {
      int row = mt * 16 + m15;
      int idx = (row * 512 + ((ks * 64 + g * 16) ^ ((row & 7) << 4))) >> 4;
      ah[mt] = __builtin_bit_cast(short8, ldsh[idx]);
      al_[mt] = __builtin_bit_cast(short8, ldsl[idx]);
    }
#pragma unroll
    for (int nt = 0; nt < 4; ++nt) {
      int n = w * 64 + nt * 16 + m15;
      bh[nt] = __builtin_bit_cast(short8, wh4[n * 32 + ks * 4 + g]);
      bl[nt] = __builtin_bit_cast(short8, wl4[n * 32 + ks * 4 + g]);
    }
#pragma unroll
    for (int mt = 0; mt < 4; ++mt)
#pragma unroll
      for (int nt = 0; nt < 4; ++nt) {
        acc[mt][nt] = __builtin_amdgcn_mfma_f32_16x16x32_bf16(
            ah[mt], bh[nt], acc[mt][nt], 0, 0, 0);
        acc[mt][nt] = __builtin_amdgcn_mfma_f32_16x16x32_bf16(
            ah[mt], bl[nt], acc[mt][nt], 0, 0, 0);
        acc[mt][nt] = __builtin_amdgcn_mfma_f32_16x16x32_bf16(
            al_[mt], bh[nt], acc[mt][nt], 0, 0, 0);
      }
  }

  // epilogue: ft (bf16) + fused a1/a2 (f32)
  float al[4], ar[4];
#pragma unroll
  for (int nt = 0; nt < 4; ++nt) {
    al[nt] = attn_l[w * 64 + nt * 16 + m15];
    ar[nt] = attn_r[w * 64 + nt * 16 + m15];
  }
#pragma unroll
  for (int mt = 0; mt < 4; ++mt) {
#pragma unroll
    for (int r = 0; r < 4; ++r) {
      int rloc = mt * 16 + g * 4 + r;  // C/D: row=(lane>>4)*4+reg (m89)
      int row = row0 + rloc;
      float v1 = 0.f, v2 = 0.f;
#pragma unroll
      for (int nt = 0; nt < 4; ++nt) {
        float v = acc[mt][nt][r];
        v1 += v * al[nt];
        v2 += v * ar[nt];
        if (row < N)
          ftb[(size_t)row * HD + w * 64 + nt * 16 + m15] = f2bf(v);
      }
#pragma unroll
      for (int o = 8; o; o >>= 1) {
        v1 += __shfl_xor(v1, o);
        v2 += __shfl_xor(v2, o);
      }
      if (m15 == 0 && row < N) {
        a1[(size_t)row * HEADS + w] = v1;
        a2[(size_t)row * HEADS + w] = v2;
      }
    }
  }
}

// ---------------------------------------------------------------------------
// K3: single-block exclusive scan deg -> rowptr
// ---------------------------------------------------------------------------
__global__ __launch_bounds__(1024) void scan_kernel(
    const int* __restrict__ deg, int* __restrict__ rowptr, int n) {
  __shared__ int buf[1024];
  const int tid = threadIdx.x;
  const int chunk = (n + 1023) >> 10;
  const int b = tid * chunk;
  const int e_ = min(b + chunk, n);
  int s = 0;
  for (int i = b; i < e_; ++i) s += deg[i];
  buf[tid] = s;
  __syncthreads();
  for (int d = 1; d < 1024; d <<= 1) {
    int v = (tid >= d) ? buf[tid - d] : 0;
    __syncthreads();
    buf[tid] += v;
    __syncthreads();
  }
  int off = (tid > 0) ? buf[tid - 1] : 0;
  for (int i = b; i < e_; ++i) {
    rowptr[i] = off;
    off += deg[i];
  }
  if (b < n && e_ == n) rowptr[n] = off;
}

// ---------------------------------------------------------------------------
// K4: fused edge-score + CSR scatter.
// ---------------------------------------------------------------------------
__global__ __launch_bounds__(256) void edge_scatter_kernel(
    const float* __restrict__ a1, const float* __restrict__ a2,
    const int* __restrict__ src, const int* __restrict__ dst,
    const int* __restrict__ rowptr, int* __restrict__ cursor,
    float* __restrict__ csr_e, int* __restrict__ csr_src, int E) {
  int i = blockIdx.x * blockDim.x + threadIdx.x;
  if (i >= E) return;
  int s_ = src[i], d_ = dst[i];
  float4 va = ((const float4*)a1)[s_];
  float4 vb = ((const float4*)a2)[d_];
  float4 r;
  r.x = lrelu(va.x + vb.x);
  r.y = lrelu(va.y + vb.y);
  r.z = lrelu(va.z + vb.z);
  r.w = lrelu(va.w + vb.w);
  int pos = rowptr[d_] + atomicAdd(&cursor[d_], 1);
  ((float4*)csr_e)[pos] = r;
  csr_src[pos] = s_;
}

// ---------------------------------------------------------------------------
// K5: per-dst softmax + weighted aggregation + ELU.
// ONE WAVE PER NODE. Lane owns 4 output dims (head = lane>>4). Per edge the
// wave gathers the full 512B ft row with one uint2 (8B) load per lane.
// Softmax max/sum per 16-lane head group; weights cached in per-wave LDS.
// Gather loop unrolled x4 (4 rows in flight per wave).
// ---------------------------------------------------------------------------
__global__ __launch_bounds__(256) void aggregate_kernel(
    const unsigned short* __restrict__ ftb, const float* __restrict__ csr_e,
    const int* __restrict__ csr_src, const int* __restrict__ rowptr,
    float* __restrict__ out, int N) {
  __shared__ float exw[4][HEADS][MAXE];
  const int tid = threadIdx.x;
  const int wv = tid >> 6;
  const int lane = tid & 63;
  const int n = blockIdx.x * 4 + wv;
  if (n >= N) return;
  const int hg = lane >> 4;   // head group of this lane
  const int l16 = lane & 15;
  const int start = rowptr[n];
  const int cnt = rowptr[n + 1] - start;

  // pass 1: per-head max over edges (16 lanes per head)
  float mx = -1e30f;
  for (int j = l16; j < cnt; j += 16)
    mx = fmaxf(mx, csr_e[(size_t)(start + j) * HEADS + hg]);
#pragma unroll
  for (int o = 8; o; o >>= 1) mx = fmaxf(mx, __shfl_xor(mx, o));

  // pass 2: exp-sum, cache unnormalized weights in LDS
  float sm = 0.f;
  for (int j = l16; j < cnt; j += 16) {
    float ex = __expf(csr_e[(size_t)(start + j) * HEADS + hg] - mx);
    if (j < MAXE) exw[wv][hg][j] = ex;
    sm += ex;
  }
#pragma unroll
  for (int o = 8; o; o >>= 1) sm += __shfl_xor(sm, o);
  float inv = (cnt > 0) ? 1.f / sm : 0.f;
  // exw written and read by the same wave — no barrier needed

  // pass 3: gather + weighted accumulate (4 dims per lane)
  float a0 = 0.f, b0 = 0.f, c0 = 0.f, d0 = 0.f;
  const int lim = min(cnt, MAXE);
  const size_t col = (size_t)(lane * 4);
  int j = 0;
  for (; j + 4 <= lim; j += 4) {
    int s0 = csr_src[start + j + 0];
    int s1 = csr_src[start + j + 1];
    int s2 = csr_src[start + j + 2];
    int s3 = csr_src[start + j + 3];
    uint2 u0 = *(const uint2*)&ftb[(size_t)s0 * HD + col];
    uint2 u1 = *(const uint2*)&ftb[(size_t)s1 * HD + col];
    uint2 u2 = *(const uint2*)&ftb[(size_t)s2 * HD + col];
    uint2 u3 = *(const uint2*)&ftb[(size_t)s3 * HD + col];
    float w0 = exw[wv][hg][j + 0], w1 = exw[wv][hg][j + 1];
    float w2 = exw[wv][hg][j + 2], w3 = exw[wv][hg][j + 3];
    a0 += w0 * bflo(u0.x); b0 += w0 * bfhi(u0.x);
    c0 += w0 * bflo(u0.y); d0 += w0 * bfhi(u0.y);
    a0 += w1 * bflo(u1.x); b0 += w1 * bfhi(u1.x);
    c0 += w1 * bflo(u1.y); d0 += w1 * bfhi(u1.y);
    a0 += w2 * bflo(u2.x); b0 += w2 * bfhi(u2.x);
    c0 += w2 * bflo(u2.y); d0 += w2 * bfhi(u2.y);
    a0 += w3 * bflo(u3.x); b0 += w3 * bfhi(u3.x);
    c0 += w3 * bflo(u3.y); d0 += w3 * bfhi(u3.y);
  }
  for (; j < cnt; ++j) {
    float w = (j < MAXE) ? exw[wv][hg][j]
                         : __expf(csr_e[(size_t)(start + j) * HEADS + hg] - mx);
    uint2 u = *(const uint2*)&ftb[(size_t)csr_src[start + j] * HD + col];
    a0 += w * bflo(u.x); b0 += w * bfhi(u.x);
    c0 += w * bflo(u.y); d0 += w * bfhi(u.y);
  }
  a0 *= inv; b0 *= inv; c0 *= inv; d0 *= inv;
  float4 o4;
  o4.x = a0 > 0.f ? a0 : (__expf(a0) - 1.f);
  o4.y = b0 > 0.f ? b0 : (__expf(b0) - 1.f);
  o4.z = c0 > 0.f ? c0 : (__expf(c0) - 1.f);
  o4.w = d0 > 0.f ? d0 : (__expf(d0) - 1.f);
  *(float4*)&out[(size_t)n * HD + col] = o4;
}

// ---------------------------------------------------------------------------
extern "C" void kernel_launch(void* const* d_in, const int* in_sizes, int n_in,
                              void* d_out, int out_size, void* d_ws, size_t ws_size,
                              hipStream_t stream) {
  const float* feat   = (const float*)d_in[0];
  const int*   src    = (const int*)d_in[1];
  const int*   dst    = (const int*)d_in[2];
  const float* W      = (const float*)d_in[3];
  const float* attn_l = (const float*)d_in[4];
  const float* attn_r = (const float*)d_in[5];
  float* out = (float*)d_out;

  const int N = in_sizes[0] / IN_DIM;   // 50000
  const int E = in_sizes[1];            // 800000

  size_t off = 0;
  auto alloc = [&](size_t bytes) -> void* {
    void* p = (char*)d_ws + off;
    off = (off + bytes + 255) & ~(size_t)255;
    return p;
  };
  unsigned short* ftb = (unsigned short*)alloc((size_t)N * HD * 2);
  unsigned short* whi = (unsigned short*)alloc((size_t)HD * IN_DIM * 2);
  unsigned short* wlo = (unsigned short*)alloc((size_t)HD * IN_DIM * 2);
  float* a1      = (float*)alloc((size_t)N * HEADS * 4);
  float* a2      = (float*)alloc((size_t)N * HEADS * 4);
  float* csr_e   = (float*)alloc((size_t)E * HEADS * 4);
  int*   csr_src = (int*)alloc((size_t)E * 4);
  int*   deg     = (int*)alloc((size_t)2 * N * 4);   // deg + cursor
  int*   cursor  = deg + N;
  int*   rowptr  = (int*)alloc((size_t)(N + 1) * 4);
  (void)ws_size;

  hipMemsetAsync(deg, 0, (size_t)2 * N * 4, stream);

  const int eb = (E + 255) / 256;
  wcvt_kernel<<<64, 256, 0, stream>>>(W, whi, wlo);
  deg_kernel<<<eb, 256, 0, stream>>>(dst, deg, E);
  scan_kernel<<<1, 1024, 0, stream>>>(deg, rowptr, N);
  gemm_mfma<<<(N + 63) / 64, 256, 0, stream>>>(feat, whi, wlo, attn_l, attn_r,
                                               ftb, a1, a2, N);
  edge_scatter_kernel<<<eb, 256, 0, stream>>>(a1, a2, src, dst, rowptr, cursor,
                                              csr_e, csr_src, E);
  aggregate_kernel<<<(N + 3) / 4, 256, 0, stream>>>(ftb, csr_e, csr_src,
                                                    rowptr, out, N);
}

// Round 6
// 259.763 us; speedup vs baseline: 3.4704x; 1.0749x over previous
//
#include <hip/hip_runtime.h>
#include <hip/hip_bf16.h>

#define ALPHA 0.2f
#define IN_DIM 256
#define HD 256      // HEADS*OUT_DIM
#define HEADS 4
#define MAXE 256    // LDS-cached weights per node (fallback recompute beyond)

typedef short short8 __attribute__((ext_vector_type(8)));
typedef float f32x4 __attribute__((ext_vector_type(4)));

__device__ __forceinline__ float lrelu(float x) { return x > 0.f ? x : ALPHA * x; }

__device__ __forceinline__ unsigned short f2bf(float x) {  // RTNE f32->bf16
  unsigned int u = __builtin_bit_cast(unsigned int, x);
  unsigned int r = (u + 0x7fffu + ((u >> 16) & 1u)) >> 16;
  return (unsigned short)r;
}
__device__ __forceinline__ float bf2f(unsigned short h) {
  unsigned int u = ((unsigned int)h) << 16;
  return __builtin_bit_cast(float, u);
}
// packed bf16 pair -> f32 (low / high element)
__device__ __forceinline__ float bflo(unsigned int u) {
  return __builtin_bit_cast(float, u << 16);
}
__device__ __forceinline__ float bfhi(unsigned int u) {
  return __builtin_bit_cast(float, u & 0xffff0000u);
}

// ---------------------------------------------------------------------------
// K0: W (f32 [256][256]) -> hi/lo bf16, PERMUTED into MFMA-fragment order:
//   uint4 dst idx = (((head*8+ks)*4+nt)*4+g)*16 + m15
// so a wave's B-fragment load (lane = g*16+m15) is one contiguous 1KB line.
// One thread per source uint4 (8 floats): 8192 threads.
// ---------------------------------------------------------------------------
__global__ __launch_bounds__(256) void wcvt_kernel(
    const float* __restrict__ W, uint4* __restrict__ whi,
    uint4* __restrict__ wlo) {
  int u = blockIdx.x * 256 + threadIdx.x;   // source uint4 index
  int n = u >> 5, c = u & 31;               // row, k-chunk
  int ks = c >> 2, g = c & 3;
  int head = n >> 6, nt = (n >> 4) & 3, m15 = n & 15;
  const float* gp = &W[(size_t)u * 8];
  float4 f0 = *(const float4*)gp;
  float4 f1 = *(const float4*)(gp + 4);
  float ff[8] = {f0.x, f0.y, f0.z, f0.w, f1.x, f1.y, f1.z, f1.w};
  unsigned int hh[8], ll[8];
#pragma unroll
  for (int k = 0; k < 8; ++k) {
    unsigned short h = f2bf(ff[k]);
    hh[k] = h;
    ll[k] = f2bf(ff[k] - bf2f(h));
  }
  uint4 ph, pl;
  ph.x = hh[0] | (hh[1] << 16); ph.y = hh[2] | (hh[3] << 16);
  ph.z = hh[4] | (hh[5] << 16); ph.w = hh[6] | (hh[7] << 16);
  pl.x = ll[0] | (ll[1] << 16); pl.y = ll[2] | (ll[3] << 16);
  pl.z = ll[4] | (ll[5] << 16); pl.w = ll[6] | (ll[7] << 16);
  int dst = (((head * 8 + ks) * 4 + nt) * 4 + g) * 16 + m15;
  whi[dst] = ph;
  wlo[dst] = pl;
}

// ---------------------------------------------------------------------------
// K0b: degree histogram
// ---------------------------------------------------------------------------
__global__ __launch_bounds__(256) void deg_kernel(
    const int* __restrict__ dst, int* __restrict__ deg, int E) {
  int i = blockIdx.x * blockDim.x + threadIdx.x;
  if (i < E) atomicAdd(&deg[dst[i]], 1);
}

// ---------------------------------------------------------------------------
// K1: split-precision MFMA projection (triple MFMA: hi*hi + hi*lo + lo*hi).
// M-tile 32 rows (LDS 32KB -> 4-5 blocks/CU), N = 256 (wave w owns head w).
// A hi/lo in LDS, XOR-swizzled; B from L2 in permuted (coalesced) layout.
// Fused a1/a2 epilogue.
// ---------------------------------------------------------------------------
__global__ __launch_bounds__(256, 4) void gemm_mfma(
    const float* __restrict__ feat, const uint4* __restrict__ whi,
    const uint4* __restrict__ wlo,
    const float* __restrict__ attn_l, const float* __restrict__ attn_r,
    unsigned short* __restrict__ ftb, float* __restrict__ a1,
    float* __restrict__ a2, int N) {
  __shared__ uint4 ldsh[1024];  // A-hi: 32 rows x 512B, swizzled
  __shared__ uint4 ldsl[1024];  // A-lo
  const int tid = threadIdx.x;
  const int row0 = blockIdx.x * 32;

#pragma unroll
  for (int it = 0; it < 4; ++it) {
    int ci = tid + it * 256;
    int row = ci >> 5, c16 = ci & 31;
    int grow = row0 + row;
    uint4 ph = uint4{0u, 0u, 0u, 0u}, pl = uint4{0u, 0u, 0u, 0u};
    if (grow < N) {
      const float* gp = &feat[(size_t)grow * IN_DIM + c16 * 8];
      float4 f0 = *(const float4*)gp;
      float4 f1 = *(const float4*)(gp + 4);
      float ff[8] = {f0.x, f0.y, f0.z, f0.w, f1.x, f1.y, f1.z, f1.w};
      unsigned int hh[8], ll[8];
#pragma unroll
      for (int k = 0; k < 8; ++k) {
        unsigned short h = f2bf(ff[k]);
        hh[k] = h;
        ll[k] = f2bf(ff[k] - bf2f(h));
      }
      ph.x = hh[0] | (hh[1] << 16); ph.y = hh[2] | (hh[3] << 16);
      ph.z = hh[4] | (hh[5] << 16); ph.w = hh[6] | (hh[7] << 16);
      pl.x = ll[0] | (ll[1] << 16); pl.y = ll[2] | (ll[3] << 16);
      pl.z = ll[4] | (ll[5] << 16); pl.w = ll[6] | (ll[7] << 16);
    }
    int idx = (row * 512 + ((c16 * 16) ^ ((row & 7) << 4))) >> 4;
    ldsh[idx] = ph;
    ldsl[idx] = pl;
  }
  __syncthreads();

  const int lane = tid & 63;
  const int w = tid >> 6;   // wave id == head id == N-quadrant
  const int m15 = lane & 15;
  const int g = lane >> 4;  // k-group 0..3

  f32x4 acc[2][4];
#pragma unroll
  for (int mt = 0; mt < 2; ++mt)
#pragma unroll
    for (int nt = 0; nt < 4; ++nt) acc[mt][nt] = f32x4{0.f, 0.f, 0.f, 0.f};

  for (int ks = 0; ks < 8; ++ks) {       // K = 8 * 32
    short8 ah[2], al_[2], bh[4], bl[4];
#pragma unroll
    for (int mt = 0; mt < 2; ++mt) {
      int row = mt * 16 + m15;
      int idx = (row * 512 + ((ks * 64 + g * 16) ^ ((row & 7) << 4))) >> 4;
      ah[mt] = __builtin_bit_cast(short8, ldsh[idx]);
      al_[mt] = __builtin_bit_cast(short8, ldsl[idx]);
    }
#pragma unroll
    for (int nt = 0; nt < 4; ++nt) {
      int idx = (((w * 8 + ks) * 4 + nt) * 4 + g) * 16 + m15;
      bh[nt] = __builtin_bit_cast(short8, whi[idx]);
      bl[nt] = __builtin_bit_cast(short8, wlo[idx]);
    }
#pragma unroll
    for (int mt = 0; mt < 2; ++mt)
#pragma unroll
      for (int nt = 0; nt < 4; ++nt) {
        acc[mt][nt] = __builtin_amdgcn_mfma_f32_16x16x32_bf16(
            ah[mt], bh[nt], acc[mt][nt], 0, 0, 0);
        acc[mt][nt] = __builtin_amdgcn_mfma_f32_16x16x32_bf16(
            ah[mt], bl[nt], acc[mt][nt], 0, 0, 0);
        acc[mt][nt] = __builtin_amdgcn_mfma_f32_16x16x32_bf16(
            al_[mt], bh[nt], acc[mt][nt], 0, 0, 0);
      }
  }

  // epilogue: ft (bf16) + fused a1/a2 (f32)
  float al[4], ar[4];
#pragma unroll
  for (int nt = 0; nt < 4; ++nt) {
    al[nt] = attn_l[w * 64 + nt * 16 + m15];
    ar[nt] = attn_r[w * 64 + nt * 16 + m15];
  }
#pragma unroll
  for (int mt = 0; mt < 2; ++mt) {
#pragma unroll
    for (int r = 0; r < 4; ++r) {
      int rloc = mt * 16 + g * 4 + r;  // C/D: row=(lane>>4)*4+reg (m89)
      int row = row0 + rloc;
      float v1 = 0.f, v2 = 0.f;
#pragma unroll
      for (int nt = 0; nt < 4; ++nt) {
        float v = acc[mt][nt][r];
        v1 += v * al[nt];
        v2 += v * ar[nt];
        if (row < N)
          ftb[(size_t)row * HD + w * 64 + nt * 16 + m15] = f2bf(v);
      }
#pragma unroll
      for (int o = 8; o; o >>= 1) {
        v1 += __shfl_xor(v1, o);
        v2 += __shfl_xor(v2, o);
      }
      if (m15 == 0 && row < N) {
        a1[(size_t)row * HEADS + w] = v1;
        a2[(size_t)row * HEADS + w] = v2;
      }
    }
  }
}

// ---------------------------------------------------------------------------
// K3: single-block exclusive scan deg -> rowptr
// ---------------------------------------------------------------------------
__global__ __launch_bounds__(1024) void scan_kernel(
    const int* __restrict__ deg, int* __restrict__ rowptr, int n) {
  __shared__ int buf[1024];
  const int tid = threadIdx.x;
  const int chunk = (n + 1023) >> 10;
  const int b = tid * chunk;
  const int e_ = min(b + chunk, n);
  int s = 0;
  for (int i = b; i < e_; ++i) s += deg[i];
  buf[tid] = s;
  __syncthreads();
  for (int d = 1; d < 1024; d <<= 1) {
    int v = (tid >= d) ? buf[tid - d] : 0;
    __syncthreads();
    buf[tid] += v;
    __syncthreads();
  }
  int off = (tid > 0) ? buf[tid - 1] : 0;
  for (int i = b; i < e_; ++i) {
    rowptr[i] = off;
    off += deg[i];
  }
  if (b < n && e_ == n) rowptr[n] = off;
}

// ---------------------------------------------------------------------------
// K4: fused edge-score + CSR scatter.
// ---------------------------------------------------------------------------
__global__ __launch_bounds__(256) void edge_scatter_kernel(
    const float* __restrict__ a1, const float* __restrict__ a2,
    const int* __restrict__ src, const int* __restrict__ dst,
    const int* __restrict__ rowptr, int* __restrict__ cursor,
    float* __restrict__ csr_e, int* __restrict__ csr_src, int E) {
  int i = blockIdx.x * blockDim.x + threadIdx.x;
  if (i >= E) return;
  int s_ = src[i], d_ = dst[i];
  float4 va = ((const float4*)a1)[s_];
  float4 vb = ((const float4*)a2)[d_];
  float4 r;
  r.x = lrelu(va.x + vb.x);
  r.y = lrelu(va.y + vb.y);
  r.z = lrelu(va.z + vb.z);
  r.w = lrelu(va.w + vb.w);
  int pos = rowptr[d_] + atomicAdd(&cursor[d_], 1);
  ((float4*)csr_e)[pos] = r;
  csr_src[pos] = s_;
}

// ---------------------------------------------------------------------------
// K5: per-dst softmax + weighted aggregation + ELU.
// ONE WAVE PER NODE. Lane owns 4 output dims (head = lane>>4). Per edge the
// wave gathers the full 512B ft row with one uint2 (8B) load per lane.
// Softmax max/sum per 16-lane head group; weights cached in per-wave LDS.
// Gather loop unrolled x4 (4 rows in flight per wave).
// ---------------------------------------------------------------------------
__global__ __launch_bounds__(256) void aggregate_kernel(
    const unsigned short* __restrict__ ftb, const float* __restrict__ csr_e,
    const int* __restrict__ csr_src, const int* __restrict__ rowptr,
    float* __restrict__ out, int N) {
  __shared__ float exw[4][HEADS][MAXE];
  const int tid = threadIdx.x;
  const int wv = tid >> 6;
  const int lane = tid & 63;
  const int n = blockIdx.x * 4 + wv;
  if (n >= N) return;
  const int hg = lane >> 4;   // head group of this lane
  const int l16 = lane & 15;
  const int start = rowptr[n];
  const int cnt = rowptr[n + 1] - start;

  // pass 1: per-head max over edges (16 lanes per head)
  float mx = -1e30f;
  for (int j = l16; j < cnt; j += 16)
    mx = fmaxf(mx, csr_e[(size_t)(start + j) * HEADS + hg]);
#pragma unroll
  for (int o = 8; o; o >>= 1) mx = fmaxf(mx, __shfl_xor(mx, o));

  // pass 2: exp-sum, cache unnormalized weights in LDS
  float sm = 0.f;
  for (int j = l16; j < cnt; j += 16) {
    float ex = __expf(csr_e[(size_t)(start + j) * HEADS + hg] - mx);
    if (j < MAXE) exw[wv][hg][j] = ex;
    sm += ex;
  }
#pragma unroll
  for (int o = 8; o; o >>= 1) sm += __shfl_xor(sm, o);
  float inv = (cnt > 0) ? 1.f / sm : 0.f;
  // exw written and read by the same wave — no barrier needed

  // pass 3: gather + weighted accumulate (4 dims per lane)
  float a0 = 0.f, b0 = 0.f, c0 = 0.f, d0 = 0.f;
  const int lim = min(cnt, MAXE);
  const size_t col = (size_t)(lane * 4);
  int j = 0;
  for (; j + 4 <= lim; j += 4) {
    int s0 = csr_src[start + j + 0];
    int s1 = csr_src[start + j + 1];
    int s2 = csr_src[start + j + 2];
    int s3 = csr_src[start + j + 3];
    uint2 u0 = *(const uint2*)&ftb[(size_t)s0 * HD + col];
    uint2 u1 = *(const uint2*)&ftb[(size_t)s1 * HD + col];
    uint2 u2 = *(const uint2*)&ftb[(size_t)s2 * HD + col];
    uint2 u3 = *(const uint2*)&ftb[(size_t)s3 * HD + col];
    float w0 = exw[wv][hg][j + 0], w1 = exw[wv][hg][j + 1];
    float w2 = exw[wv][hg][j + 2], w3 = exw[wv][hg][j + 3];
    a0 += w0 * bflo(u0.x); b0 += w0 * bfhi(u0.x);
    c0 += w0 * bflo(u0.y); d0 += w0 * bfhi(u0.y);
    a0 += w1 * bflo(u1.x); b0 += w1 * bfhi(u1.x);
    c0 += w1 * bflo(u1.y); d0 += w1 * bfhi(u1.y);
    a0 += w2 * bflo(u2.x); b0 += w2 * bfhi(u2.x);
    c0 += w2 * bflo(u2.y); d0 += w2 * bfhi(u2.y);
    a0 += w3 * bflo(u3.x); b0 += w3 * bfhi(u3.x);
    c0 += w3 * bflo(u3.y); d0 += w3 * bfhi(u3.y);
  }
  for (; j < cnt; ++j) {
    float w = (j < MAXE) ? exw[wv][hg][j]
                         : __expf(csr_e[(size_t)(start + j) * HEADS + hg] - mx);
    uint2 u = *(const uint2*)&ftb[(size_t)csr_src[start + j] * HD + col];
    a0 += w * bflo(u.x); b0 += w * bfhi(u.x);
    c0 += w * bflo(u.y); d0 += w * bfhi(u.y);
  }
  a0 *= inv; b0 *= inv; c0 *= inv; d0 *= inv;
  float4 o4;
  o4.x = a0 > 0.f ? a0 : (__expf(a0) - 1.f);
  o4.y = b0 > 0.f ? b0 : (__expf(b0) - 1.f);
  o4.z = c0 > 0.f ? c0 : (__expf(c0) - 1.f);
  o4.w = d0 > 0.f ? d0 : (__expf(d0) - 1.f);
  *(float4*)&out[(size_t)n * HD + col] = o4;
}

// ---------------------------------------------------------------------------
extern "C" void kernel_launch(void* const* d_in, const int* in_sizes, int n_in,
                              void* d_out, int out_size, void* d_ws, size_t ws_size,
                              hipStream_t stream) {
  const float* feat   = (const float*)d_in[0];
  const int*   src    = (const int*)d_in[1];
  const int*   dst    = (const int*)d_in[2];
  const float* W      = (const float*)d_in[3];
  const float* attn_l = (const float*)d_in[4];
  const float* attn_r = (const float*)d_in[5];
  float* out = (float*)d_out;

  const int N = in_sizes[0] / IN_DIM;   // 50000
  const int E = in_sizes[1];            // 800000

  size_t off = 0;
  auto alloc = [&](size_t bytes) -> void* {
    void* p = (char*)d_ws + off;
    off = (off + bytes + 255) & ~(size_t)255;
    return p;
  };
  unsigned short* ftb = (unsigned short*)alloc((size_t)N * HD * 2);
  uint4* whi     = (uint4*)alloc((size_t)HD * IN_DIM * 2);
  uint4* wlo     = (uint4*)alloc((size_t)HD * IN_DIM * 2);
  float* a1      = (float*)alloc((size_t)N * HEADS * 4);
  float* a2      = (float*)alloc((size_t)N * HEADS * 4);
  float* csr_e   = (float*)alloc((size_t)E * HEADS * 4);
  int*   csr_src = (int*)alloc((size_t)E * 4);
  int*   deg     = (int*)alloc((size_t)2 * N * 4);   // deg + cursor
  int*   cursor  = deg + N;
  int*   rowptr  = (int*)alloc((size_t)(N + 1) * 4);
  (void)ws_size;

  hipMemsetAsync(deg, 0, (size_t)2 * N * 4, stream);

  const int eb = (E + 255) / 256;
  wcvt_kernel<<<32, 256, 0, stream>>>(W, whi, wlo);
  deg_kernel<<<eb, 256, 0, stream>>>(dst, deg, E);
  scan_kernel<<<1, 1024, 0, stream>>>(deg, rowptr, N);
  gemm_mfma<<<(N + 31) / 32, 256, 0, stream>>>(feat, whi, wlo, attn_l, attn_r,
                                               ftb, a1, a2, N);
  edge_scatter_kernel<<<eb, 256, 0, stream>>>(a1, a2, src, dst, rowptr, cursor,
                                              csr_e, csr_src, E);
  aggregate_kernel<<<(N + 3) / 4, 256, 0, stream>>>(ftb, csr_e, csr_src,
                                                    rowptr, out, N);
}

// Round 7
// 192.510 us; speedup vs baseline: 4.6828x; 1.3493x over previous
//
#include <hip/hip_runtime.h>
#include <hip/hip_bf16.h>

#define ALPHA 0.2f
#define IN_DIM 256
#define HD 256      // HEADS*OUT_DIM
#define HEADS 4
#define MAXE 256    // LDS-cached weights per node (fallback recompute beyond)

typedef short short8 __attribute__((ext_vector_type(8)));
typedef float f32x4 __attribute__((ext_vector_type(4)));

__device__ __forceinline__ float lrelu(float x) { return x > 0.f ? x : ALPHA * x; }

__device__ __forceinline__ unsigned short f2bf(float x) {  // RTNE f32->bf16
  unsigned int u = __builtin_bit_cast(unsigned int, x);
  unsigned int r = (u + 0x7fffu + ((u >> 16) & 1u)) >> 16;
  return (unsigned short)r;
}
__device__ __forceinline__ float bf2f(unsigned short h) {
  unsigned int u = ((unsigned int)h) << 16;
  return __builtin_bit_cast(float, u);
}
// packed bf16 pair -> f32 (low / high element)
__device__ __forceinline__ float bflo(unsigned int u) {
  return __builtin_bit_cast(float, u << 16);
}
__device__ __forceinline__ float bfhi(unsigned int u) {
  return __builtin_bit_cast(float, u & 0xffff0000u);
}

// ---------------------------------------------------------------------------
// K0: W (f32 [256][256]) -> hi/lo bf16, PERMUTED into MFMA-fragment order:
//   uint4 dst idx = (((head*8+ks)*4+nt)*4+g)*16 + m15
// so a wave's B-fragment load (lane = g*16+m15) is one contiguous 1KB line.
// ---------------------------------------------------------------------------
__global__ __launch_bounds__(256) void wcvt_kernel(
    const float* __restrict__ W, uint4* __restrict__ whi,
    uint4* __restrict__ wlo) {
  int u = blockIdx.x * 256 + threadIdx.x;   // source uint4 index
  int n = u >> 5, c = u & 31;               // row, k-chunk
  int ks = c >> 2, g = c & 3;
  int head = n >> 6, nt = (n >> 4) & 3, m15 = n & 15;
  const float* gp = &W[(size_t)u * 8];
  float4 f0 = *(const float4*)gp;
  float4 f1 = *(const float4*)(gp + 4);
  float ff[8] = {f0.x, f0.y, f0.z, f0.w, f1.x, f1.y, f1.z, f1.w};
  unsigned int hh[8], ll[8];
#pragma unroll
  for (int k = 0; k < 8; ++k) {
    unsigned short h = f2bf(ff[k]);
    hh[k] = h;
    ll[k] = f2bf(ff[k] - bf2f(h));
  }
  uint4 ph, pl;
  ph.x = hh[0] | (hh[1] << 16); ph.y = hh[2] | (hh[3] << 16);
  ph.z = hh[4] | (hh[5] << 16); ph.w = hh[6] | (hh[7] << 16);
  pl.x = ll[0] | (ll[1] << 16); pl.y = ll[2] | (ll[3] << 16);
  pl.z = ll[4] | (ll[5] << 16); pl.w = ll[6] | (ll[7] << 16);
  int dst = (((head * 8 + ks) * 4 + nt) * 4 + g) * 16 + m15;
  whi[dst] = ph;
  wlo[dst] = pl;
}

// ---------------------------------------------------------------------------
// K0b: degree histogram
// ---------------------------------------------------------------------------
__global__ __launch_bounds__(256) void deg_kernel(
    const int* __restrict__ dst, int* __restrict__ deg, int E) {
  int i = blockIdx.x * blockDim.x + threadIdx.x;
  if (i < E) atomicAdd(&deg[dst[i]], 1);
}

// ---------------------------------------------------------------------------
// K1: split-precision MFMA projection (triple MFMA: hi*hi + hi*lo + lo*hi).
// M-tile 32 rows (LDS 32KB), N = 256 (wave w owns head w).
// ---------------------------------------------------------------------------
__global__ __launch_bounds__(256, 4) void gemm_mfma(
    const float* __restrict__ feat, const uint4* __restrict__ whi,
    const uint4* __restrict__ wlo,
    const float* __restrict__ attn_l, const float* __restrict__ attn_r,
    unsigned short* __restrict__ ftb, float* __restrict__ a1,
    float* __restrict__ a2, int N) {
  __shared__ uint4 ldsh[1024];  // A-hi: 32 rows x 512B, swizzled
  __shared__ uint4 ldsl[1024];  // A-lo
  const int tid = threadIdx.x;
  const int row0 = blockIdx.x * 32;

#pragma unroll
  for (int it = 0; it < 4; ++it) {
    int ci = tid + it * 256;
    int row = ci >> 5, c16 = ci & 31;
    int grow = row0 + row;
    uint4 ph = uint4{0u, 0u, 0u, 0u}, pl = uint4{0u, 0u, 0u, 0u};
    if (grow < N) {
      const float* gp = &feat[(size_t)grow * IN_DIM + c16 * 8];
      float4 f0 = *(const float4*)gp;
      float4 f1 = *(const float4*)(gp + 4);
      float ff[8] = {f0.x, f0.y, f0.z, f0.w, f1.x, f1.y, f1.z, f1.w};
      unsigned int hh[8], ll[8];
#pragma unroll
      for (int k = 0; k < 8; ++k) {
        unsigned short h = f2bf(ff[k]);
        hh[k] = h;
        ll[k] = f2bf(ff[k] - bf2f(h));
      }
      ph.x = hh[0] | (hh[1] << 16); ph.y = hh[2] | (hh[3] << 16);
      ph.z = hh[4] | (hh[5] << 16); ph.w = hh[6] | (hh[7] << 16);
      pl.x = ll[0] | (ll[1] << 16); pl.y = ll[2] | (ll[3] << 16);
      pl.z = ll[4] | (ll[5] << 16); pl.w = ll[6] | (ll[7] << 16);
    }
    int idx = (row * 512 + ((c16 * 16) ^ ((row & 7) << 4))) >> 4;
    ldsh[idx] = ph;
    ldsl[idx] = pl;
  }
  __syncthreads();

  const int lane = tid & 63;
  const int w = tid >> 6;   // wave id == head id == N-quadrant
  const int m15 = lane & 15;
  const int g = lane >> 4;  // k-group 0..3

  f32x4 acc[2][4];
#pragma unroll
  for (int mt = 0; mt < 2; ++mt)
#pragma unroll
    for (int nt = 0; nt < 4; ++nt) acc[mt][nt] = f32x4{0.f, 0.f, 0.f, 0.f};

  for (int ks = 0; ks < 8; ++ks) {       // K = 8 * 32
    short8 ah[2], al_[2], bh[4], bl[4];
#pragma unroll
    for (int mt = 0; mt < 2; ++mt) {
      int row = mt * 16 + m15;
      int idx = (row * 512 + ((ks * 64 + g * 16) ^ ((row & 7) << 4))) >> 4;
      ah[mt] = __builtin_bit_cast(short8, ldsh[idx]);
      al_[mt] = __builtin_bit_cast(short8, ldsl[idx]);
    }
#pragma unroll
    for (int nt = 0; nt < 4; ++nt) {
      int idx = (((w * 8 + ks) * 4 + nt) * 4 + g) * 16 + m15;
      bh[nt] = __builtin_bit_cast(short8, whi[idx]);
      bl[nt] = __builtin_bit_cast(short8, wlo[idx]);
    }
#pragma unroll
    for (int mt = 0; mt < 2; ++mt)
#pragma unroll
      for (int nt = 0; nt < 4; ++nt) {
        acc[mt][nt] = __builtin_amdgcn_mfma_f32_16x16x32_bf16(
            ah[mt], bh[nt], acc[mt][nt], 0, 0, 0);
        acc[mt][nt] = __builtin_amdgcn_mfma_f32_16x16x32_bf16(
            ah[mt], bl[nt], acc[mt][nt], 0, 0, 0);
        acc[mt][nt] = __builtin_amdgcn_mfma_f32_16x16x32_bf16(
            al_[mt], bh[nt], acc[mt][nt], 0, 0, 0);
      }
  }

  // epilogue: ft (bf16) + fused a1/a2 (f32)
  float al[4], ar[4];
#pragma unroll
  for (int nt = 0; nt < 4; ++nt) {
    al[nt] = attn_l[w * 64 + nt * 16 + m15];
    ar[nt] = attn_r[w * 64 + nt * 16 + m15];
  }
#pragma unroll
  for (int mt = 0; mt < 2; ++mt) {
#pragma unroll
    for (int r = 0; r < 4; ++r) {
      int rloc = mt * 16 + g * 4 + r;  // C/D: row=(lane>>4)*4+reg (m89)
      int row = row0 + rloc;
      float v1 = 0.f, v2 = 0.f;
#pragma unroll
      for (int nt = 0; nt < 4; ++nt) {
        float v = acc[mt][nt][r];
        v1 += v * al[nt];
        v2 += v * ar[nt];
        if (row < N)
          ftb[(size_t)row * HD + w * 64 + nt * 16 + m15] = f2bf(v);
      }
#pragma unroll
      for (int o = 8; o; o >>= 1) {
        v1 += __shfl_xor(v1, o);
        v2 += __shfl_xor(v2, o);
      }
      if (m15 == 0 && row < N) {
        a1[(size_t)row * HEADS + w] = v1;
        a2[(size_t)row * HEADS + w] = v2;
      }
    }
  }
}

// ---------------------------------------------------------------------------
// K3a: per-block partial sums of deg (4 elts/thread, int4 loads)
// ---------------------------------------------------------------------------
__global__ __launch_bounds__(256) void scan_part(
    const int* __restrict__ deg, int* __restrict__ bsum, int n) {
  const int tid = threadIdx.x;
  int base = (blockIdx.x * 256 + tid) * 4;
  int s = 0;
  if (base + 3 < n) {
    int4 v = *(const int4*)&deg[base];
    s = v.x + v.y + v.z + v.w;
  } else {
#pragma unroll
    for (int k = 0; k < 4; ++k)
      if (base + k < n) s += deg[base + k];
  }
#pragma unroll
  for (int o = 32; o; o >>= 1) s += __shfl_xor(s, o);
  __shared__ int ws[4];
  if ((tid & 63) == 0) ws[tid >> 6] = s;
  __syncthreads();
  if (tid == 0) bsum[blockIdx.x] = ws[0] + ws[1] + ws[2] + ws[3];
}

// ---------------------------------------------------------------------------
// K3b: single-wave scan of block sums -> exclusive block offsets + rowptr[n]
// (requires nb <= 64)
// ---------------------------------------------------------------------------
__global__ __launch_bounds__(64) void scan_block(
    const int* __restrict__ bsum, int* __restrict__ boff,
    int* __restrict__ rowptr, int nb, int n) {
  int lane = threadIdx.x;
  int v = (lane < nb) ? bsum[lane] : 0;
  int orig = v;
#pragma unroll
  for (int o = 1; o < 64; o <<= 1) {
    int t = __shfl_up(v, o);
    if (lane >= o) v += t;
  }
  if (lane < nb) boff[lane] = v - orig;
  if (lane == nb - 1) rowptr[n] = v;
}

// ---------------------------------------------------------------------------
// K3c: emit rowptr (block-wide scan over 256 thread sums + int4 stores)
// ---------------------------------------------------------------------------
__global__ __launch_bounds__(256) void scan_emit(
    const int* __restrict__ deg, const int* __restrict__ boff,
    int* __restrict__ rowptr, int n) {
  __shared__ int buf[256];
  const int tid = threadIdx.x;
  int base = (blockIdx.x * 256 + tid) * 4;
  int d0 = 0, d1 = 0, d2 = 0, d3 = 0;
  if (base + 3 < n) {
    int4 v = *(const int4*)&deg[base];
    d0 = v.x; d1 = v.y; d2 = v.z; d3 = v.w;
  } else {
    if (base < n) d0 = deg[base];
    if (base + 1 < n) d1 = deg[base + 1];
    if (base + 2 < n) d2 = deg[base + 2];
    if (base + 3 < n) d3 = deg[base + 3];
  }
  int s = d0 + d1 + d2 + d3;
  buf[tid] = s;
  __syncthreads();
  for (int d = 1; d < 256; d <<= 1) {
    int v = (tid >= d) ? buf[tid - d] : 0;
    __syncthreads();
    buf[tid] += v;
    __syncthreads();
  }
  int excl = buf[tid] - s + boff[blockIdx.x];
  if (base + 3 < n) {
    int4 o;
    o.x = excl;
    o.y = excl + d0;
    o.z = excl + d0 + d1;
    o.w = excl + d0 + d1 + d2;
    *(int4*)&rowptr[base] = o;
  } else {
    int off = excl;
    if (base < n)     { rowptr[base] = off;     off += d0; }
    if (base + 1 < n) { rowptr[base + 1] = off; off += d1; }
    if (base + 2 < n) { rowptr[base + 2] = off; off += d2; }
    if (base + 3 < n) { rowptr[base + 3] = off; }
  }
}

// ---------------------------------------------------------------------------
// K4: fused edge-score + CSR scatter.
// ---------------------------------------------------------------------------
__global__ __launch_bounds__(256) void edge_scatter_kernel(
    const float* __restrict__ a1, const float* __restrict__ a2,
    const int* __restrict__ src, const int* __restrict__ dst,
    const int* __restrict__ rowptr, int* __restrict__ cursor,
    float* __restrict__ csr_e, int* __restrict__ csr_src, int E) {
  int i = blockIdx.x * blockDim.x + threadIdx.x;
  if (i >= E) return;
  int s_ = src[i], d_ = dst[i];
  float4 va = ((const float4*)a1)[s_];
  float4 vb = ((const float4*)a2)[d_];
  float4 r;
  r.x = lrelu(va.x + vb.x);
  r.y = lrelu(va.y + vb.y);
  r.z = lrelu(va.z + vb.z);
  r.w = lrelu(va.w + vb.w);
  int pos = rowptr[d_] + atomicAdd(&cursor[d_], 1);
  ((float4*)csr_e)[pos] = r;
  csr_src[pos] = s_;
}

// ---------------------------------------------------------------------------
// K5: per-dst softmax + weighted aggregation + ELU. One wave per node.
// ---------------------------------------------------------------------------
__global__ __launch_bounds__(256) void aggregate_kernel(
    const unsigned short* __restrict__ ftb, const float* __restrict__ csr_e,
    const int* __restrict__ csr_src, const int* __restrict__ rowptr,
    float* __restrict__ out, int N) {
  __shared__ float exw[4][HEADS][MAXE];
  const int tid = threadIdx.x;
  const int wv = tid >> 6;
  const int lane = tid & 63;
  const int n = blockIdx.x * 4 + wv;
  if (n >= N) return;
  const int hg = lane >> 4;   // head group of this lane
  const int l16 = lane & 15;
  const int start = rowptr[n];
  const int cnt = rowptr[n + 1] - start;

  // pass 1: per-head max over edges (16 lanes per head)
  float mx = -1e30f;
  for (int j = l16; j < cnt; j += 16)
    mx = fmaxf(mx, csr_e[(size_t)(start + j) * HEADS + hg]);
#pragma unroll
  for (int o = 8; o; o >>= 1) mx = fmaxf(mx, __shfl_xor(mx, o));

  // pass 2: exp-sum, cache unnormalized weights in LDS
  float sm = 0.f;
  for (int j = l16; j < cnt; j += 16) {
    float ex = __expf(csr_e[(size_t)(start + j) * HEADS + hg] - mx);
    if (j < MAXE) exw[wv][hg][j] = ex;
    sm += ex;
  }
#pragma unroll
  for (int o = 8; o; o >>= 1) sm += __shfl_xor(sm, o);
  float inv = (cnt > 0) ? 1.f / sm : 0.f;
  // exw written and read by the same wave — no barrier needed

  // pass 3: gather + weighted accumulate (4 dims per lane)
  float a0 = 0.f, b0 = 0.f, c0 = 0.f, d0 = 0.f;
  const int lim = min(cnt, MAXE);
  const size_t col = (size_t)(lane * 4);
  int j = 0;
  for (; j + 4 <= lim; j += 4) {
    int s0 = csr_src[start + j + 0];
    int s1 = csr_src[start + j + 1];
    int s2 = csr_src[start + j + 2];
    int s3 = csr_src[start + j + 3];
    uint2 u0 = *(const uint2*)&ftb[(size_t)s0 * HD + col];
    uint2 u1 = *(const uint2*)&ftb[(size_t)s1 * HD + col];
    uint2 u2 = *(const uint2*)&ftb[(size_t)s2 * HD + col];
    uint2 u3 = *(const uint2*)&ftb[(size_t)s3 * HD + col];
    float w0 = exw[wv][hg][j + 0], w1 = exw[wv][hg][j + 1];
    float w2 = exw[wv][hg][j + 2], w3 = exw[wv][hg][j + 3];
    a0 += w0 * bflo(u0.x); b0 += w0 * bfhi(u0.x);
    c0 += w0 * bflo(u0.y); d0 += w0 * bfhi(u0.y);
    a0 += w1 * bflo(u1.x); b0 += w1 * bfhi(u1.x);
    c0 += w1 * bflo(u1.y); d0 += w1 * bfhi(u1.y);
    a0 += w2 * bflo(u2.x); b0 += w2 * bfhi(u2.x);
    c0 += w2 * bflo(u2.y); d0 += w2 * bfhi(u2.y);
    a0 += w3 * bflo(u3.x); b0 += w3 * bfhi(u3.x);
    c0 += w3 * bflo(u3.y); d0 += w3 * bfhi(u3.y);
  }
  for (; j < cnt; ++j) {
    float w = (j < MAXE) ? exw[wv][hg][j]
                         : __expf(csr_e[(size_t)(start + j) * HEADS + hg] - mx);
    uint2 u = *(const uint2*)&ftb[(size_t)csr_src[start + j] * HD + col];
    a0 += w * bflo(u.x); b0 += w * bfhi(u.x);
    c0 += w * bflo(u.y); d0 += w * bfhi(u.y);
  }
  a0 *= inv; b0 *= inv; c0 *= inv; d0 *= inv;
  float4 o4;
  o4.x = a0 > 0.f ? a0 : (__expf(a0) - 1.f);
  o4.y = b0 > 0.f ? b0 : (__expf(b0) - 1.f);
  o4.z = c0 > 0.f ? c0 : (__expf(c0) - 1.f);
  o4.w = d0 > 0.f ? d0 : (__expf(d0) - 1.f);
  *(float4*)&out[(size_t)n * HD + col] = o4;
}

// ---------------------------------------------------------------------------
extern "C" void kernel_launch(void* const* d_in, const int* in_sizes, int n_in,
                              void* d_out, int out_size, void* d_ws, size_t ws_size,
                              hipStream_t stream) {
  const float* feat   = (const float*)d_in[0];
  const int*   src    = (const int*)d_in[1];
  const int*   dst    = (const int*)d_in[2];
  const float* W      = (const float*)d_in[3];
  const float* attn_l = (const float*)d_in[4];
  const float* attn_r = (const float*)d_in[5];
  float* out = (float*)d_out;

  const int N = in_sizes[0] / IN_DIM;   // 50000
  const int E = in_sizes[1];            // 800000

  size_t off = 0;
  auto alloc = [&](size_t bytes) -> void* {
    void* p = (char*)d_ws + off;
    off = (off + bytes + 255) & ~(size_t)255;
    return p;
  };
  unsigned short* ftb = (unsigned short*)alloc((size_t)N * HD * 2);
  uint4* whi     = (uint4*)alloc((size_t)HD * IN_DIM * 2);
  uint4* wlo     = (uint4*)alloc((size_t)HD * IN_DIM * 2);
  float* a1      = (float*)alloc((size_t)N * HEADS * 4);
  float* a2      = (float*)alloc((size_t)N * HEADS * 4);
  float* csr_e   = (float*)alloc((size_t)E * HEADS * 4);
  int*   csr_src = (int*)alloc((size_t)E * 4);
  int*   deg     = (int*)alloc((size_t)2 * N * 4);   // deg + cursor
  int*   cursor  = deg + N;
  int*   rowptr  = (int*)alloc((size_t)(N + 1) * 4);
  int*   bsum    = (int*)alloc(64 * 4);
  int*   boff    = (int*)alloc(64 * 4);
  (void)ws_size;

  hipMemsetAsync(deg, 0, (size_t)2 * N * 4, stream);

  const int eb = (E + 255) / 256;
  const int nb = (N + 1023) / 1024;   // scan blocks (<= 64)
  wcvt_kernel<<<32, 256, 0, stream>>>(W, whi, wlo);
  deg_kernel<<<eb, 256, 0, stream>>>(dst, deg, E);
  scan_part<<<nb, 256, 0, stream>>>(deg, bsum, N);
  scan_block<<<1, 64, 0, stream>>>(bsum, boff, rowptr, nb, N);
  scan_emit<<<nb, 256, 0, stream>>>(deg, boff, rowptr, N);
  gemm_mfma<<<(N + 31) / 32, 256, 0, stream>>>(feat, whi, wlo, attn_l, attn_r,
                                               ftb, a1, a2, N);
  edge_scatter_kernel<<<eb, 256, 0, stream>>>(a1, a2, src, dst, rowptr, cursor,
                                              csr_e, csr_src, E);
  aggregate_kernel<<<(N + 3) / 4, 256, 0, stream>>>(ftb, csr_e, csr_src,
                                                    rowptr, out, N);
}